// Round 1
// baseline (224.391 us; speedup 1.0000x reference)
//
#include <hip/hip_runtime.h>
#include <cmath>

#define EPS_BN 1e-5f

typedef __bf16 bf16;
typedef __bf16 bf16x4 __attribute__((ext_vector_type(4)));
typedef __bf16 bf16x8 __attribute__((ext_vector_type(8)));
typedef float  f32x4  __attribute__((ext_vector_type(4)));

// ---------------------------------------------------------------------------
// Kernel 1: all preprocessing elementwise work in one launch. (unchanged R6)
// ---------------------------------------------------------------------------
__global__ __launch_bounds__(256) void conv_all_kernel(
    const float* __restrict__ x,
    const float* __restrict__ qdw, const float* __restrict__ qscale,
    const float* __restrict__ qbias, const float* __restrict__ qmean,
    const float* __restrict__ qvar,
    const float* __restrict__ kdw, const float* __restrict__ kscale,
    const float* __restrict__ kbias, const float* __restrict__ kmean,
    const float* __restrict__ kvar,
    const float* __restrict__ vdw, const float* __restrict__ vscale,
    const float* __restrict__ vbias, const float* __restrict__ vmean,
    const float* __restrict__ vvar,
    const float* __restrict__ qpw, const float* __restrict__ kpw,
    const float* __restrict__ vpw,
    bf16* __restrict__ qhi, bf16* __restrict__ qlo,
    bf16* __restrict__ khi, bf16* __restrict__ klo,
    bf16* __restrict__ vhi, bf16* __restrict__ vlo,
    bf16* __restrict__ wt) {
    const int WW = 56, C = 192;
    int bid = blockIdx.x;

    if (bid < 4704) {
        int idx = bid * 256 + threadIdx.x;
        int p  = idx / 48;
        int c4 = (idx - p * 48) * 4;
        int b  = p / 3136;
        int rem = p - b * 3136;
        int oy = rem / 56;
        int ox = rem - oy * 56;
        const float* xb = x + (size_t)b * 3136 * C;

        float4 sc = *(const float4*)&qscale[c4];
        float4 vr = *(const float4*)&qvar[c4];
        float4 bi = *(const float4*)&qbias[c4];
        float4 mn = *(const float4*)&qmean[c4];
        float aA[4] = {sc.x * rsqrtf(vr.x + EPS_BN), sc.y * rsqrtf(vr.y + EPS_BN),
                       sc.z * rsqrtf(vr.z + EPS_BN), sc.w * rsqrtf(vr.w + EPS_BN)};
        float aB[4] = {bi.x - mn.x * aA[0], bi.y - mn.y * aA[1],
                       bi.z - mn.z * aA[2], bi.w - mn.w * aA[3]};
        float s[4] = {0.f, 0.f, 0.f, 0.f};
#pragma unroll
        for (int ky = 0; ky < 3; ky++) {
            int iy = oy + ky - 1;
            bool yok = (iy >= 0) && (iy < 56);
#pragma unroll
            for (int kx = 0; kx < 3; kx++) {
                int ix = ox + kx - 1;
                if (yok && ix >= 0 && ix < WW) {
                    float4 xv = *(const float4*)&xb[((size_t)iy * WW + ix) * C + c4];
                    float4 wv = *(const float4*)&qdw[(ky * 3 + kx) * C + c4];
                    s[0] += xv.x * wv.x; s[1] += xv.y * wv.y;
                    s[2] += xv.z * wv.z; s[3] += xv.w * wv.w;
                }
            }
        }
        bf16x4 hv, lv;
#pragma unroll
        for (int j = 0; j < 4; j++) {
            float av = s[j] * aA[j] + aB[j];
            bf16 hh = (bf16)av;
            hv[j] = hh;
            lv[j] = (bf16)(av - (float)hh);
        }
        *(bf16x4*)&qhi[(size_t)p * C + c4] = hv;
        *(bf16x4*)&qlo[(size_t)p * C + c4] = lv;
    } else if (bid < 5880) {
        int idx = (bid - 4704) * 256 + threadIdx.x;
        int p  = idx / 48;
        int c4 = (idx - p * 48) * 4;
        int b  = p / 784;
        int rem = p - b * 784;
        int oy = rem / 28;
        int ox = rem - oy * 28;
        const float* xb = x + (size_t)b * 3136 * C;

        float ks[4] = {0.f, 0.f, 0.f, 0.f};
        float vs[4] = {0.f, 0.f, 0.f, 0.f};
#pragma unroll
        for (int ky = 0; ky < 3; ky++) {
            int iy = oy * 2 + ky;
            bool yok = iy < 56;
#pragma unroll
            for (int kx = 0; kx < 3; kx++) {
                int ix = ox * 2 + kx;
                if (yok && ix < WW) {
                    float4 xv = *(const float4*)&xb[((size_t)iy * WW + ix) * C + c4];
                    float4 kw = *(const float4*)&kdw[(ky * 3 + kx) * C + c4];
                    float4 vw = *(const float4*)&vdw[(ky * 3 + kx) * C + c4];
                    ks[0] += xv.x * kw.x; ks[1] += xv.y * kw.y;
                    ks[2] += xv.z * kw.z; ks[3] += xv.w * kw.w;
                    vs[0] += xv.x * vw.x; vs[1] += xv.y * vw.y;
                    vs[2] += xv.z * vw.z; vs[3] += xv.w * vw.w;
                }
            }
        }
        float4 ksc = *(const float4*)&kscale[c4];
        float4 kvr = *(const float4*)&kvar[c4];
        float4 kbi = *(const float4*)&kbias[c4];
        float4 kmn = *(const float4*)&kmean[c4];
        float4 vsc = *(const float4*)&vscale[c4];
        float4 vvr = *(const float4*)&vvar[c4];
        float4 vbi = *(const float4*)&vbias[c4];
        float4 vmn = *(const float4*)&vmean[c4];
        float kA[4] = {ksc.x * rsqrtf(kvr.x + EPS_BN), ksc.y * rsqrtf(kvr.y + EPS_BN),
                       ksc.z * rsqrtf(kvr.z + EPS_BN), ksc.w * rsqrtf(kvr.w + EPS_BN)};
        float kB[4] = {kbi.x - kmn.x * kA[0], kbi.y - kmn.y * kA[1],
                       kbi.z - kmn.z * kA[2], kbi.w - kmn.w * kA[3]};
        float vA[4] = {vsc.x * rsqrtf(vvr.x + EPS_BN), vsc.y * rsqrtf(vvr.y + EPS_BN),
                       vsc.z * rsqrtf(vvr.z + EPS_BN), vsc.w * rsqrtf(vvr.w + EPS_BN)};
        float vB[4] = {vbi.x - vmn.x * vA[0], vbi.y - vmn.y * vA[1],
                       vbi.z - vmn.z * vA[2], vbi.w - vmn.w * vA[3]};
        bf16x4 kh, kl, vh, vl;
#pragma unroll
        for (int j = 0; j < 4; j++) {
            float kf = ks[j] * kA[j] + kB[j];
            float vf = vs[j] * vA[j] + vB[j];
            bf16 h1 = (bf16)kf; kh[j] = h1; kl[j] = (bf16)(kf - (float)h1);
            bf16 h2 = (bf16)vf; vh[j] = h2; vl[j] = (bf16)(vf - (float)h2);
        }
        *(bf16x4*)&khi[(size_t)p * C + c4] = kh;
        *(bf16x4*)&klo[(size_t)p * C + c4] = kl;
        *(bf16x4*)&vhi[(size_t)p * C + c4] = vh;
        *(bf16x4*)&vlo[(size_t)p * C + c4] = vl;
    } else {
        int idx = (bid - 5880) * 256 + threadIdx.x;
        if (idx < 3 * 36864) {
            int mat = idx / 36864, r = idx % 36864;
            int n = r / 192, k = r - n * 192;
            const float* src = (mat == 0) ? qpw : (mat == 1) ? kpw : vpw;
            wt[idx] = (bf16)src[k * 192 + n];
        }
    }
}

// ---------------------------------------------------------------------------
// Kernel 2: all three pointwise GEMMs in one launch. (unchanged R6)
// ---------------------------------------------------------------------------
__global__ __launch_bounds__(256) void gemm_all_kernel(
    const bf16* __restrict__ qhi, const bf16* __restrict__ qlo,
    const bf16* __restrict__ khi, const bf16* __restrict__ klo,
    const bf16* __restrict__ vhi, const bf16* __restrict__ vlo,
    const bf16* __restrict__ wt,
    bf16* __restrict__ qbuf, bf16* __restrict__ kbuf, bf16* __restrict__ vtbuf) {
    __shared__ bf16 Ws[192][200];
    int t = threadIdx.x;
    int bid = blockIdx.x;

    int mode, mt;
    const bf16 *Ahi, *Alo, *Wsrc;
    if (bid < 392)      { mode = 0; mt = bid;       Ahi = qhi; Alo = qlo; Wsrc = wt; }
    else if (bid < 490) { mode = 1; mt = bid - 392; Ahi = khi; Alo = klo; Wsrc = wt + 36864; }
    else                { mode = 2; mt = bid - 490; Ahi = vhi; Alo = vlo; Wsrc = wt + 73728; }

#pragma unroll
    for (int it = 0; it < 18; it++) {
        int idx = it * 256 + t;
        int n = idx / 24, ck = idx - n * 24;
        *(uint4*)&Ws[n][ck * 8] = *(const uint4*)&Wsrc[n * 192 + ck * 8];
    }
    __syncthreads();

    int lane = t & 63, wid = t >> 6;
    int l16 = lane & 15, quad = lane >> 4;
    int wrow = wid * 16;
    int m0 = mt * 64;

    f32x4 acc[12];
#pragma unroll
    for (int n = 0; n < 12; n++) acc[n] = f32x4{0.f, 0.f, 0.f, 0.f};

    const bf16* arh = Ahi + (size_t)(m0 + wrow + l16) * 192;
    const bf16* arl = Alo + (size_t)(m0 + wrow + l16) * 192;
#pragma unroll
    for (int kc = 0; kc < 6; kc++) {
        bf16x8 ah = *(const bf16x8*)(arh + kc * 32 + quad * 8);
        bf16x8 al = *(const bf16x8*)(arl + kc * 32 + quad * 8);
#pragma unroll
        for (int n = 0; n < 12; n++) {
            bf16x8 bfr = *(const bf16x8*)&Ws[n * 16 + l16][kc * 32 + quad * 8];
            acc[n] = __builtin_amdgcn_mfma_f32_16x16x32_bf16(al, bfr, acc[n], 0, 0, 0);
            acc[n] = __builtin_amdgcn_mfma_f32_16x16x32_bf16(ah, bfr, acc[n], 0, 0, 0);
        }
    }

    if (mode == 2) {
#pragma unroll
        for (int reg = 0; reg < 4; reg++) {
            int row = m0 + wrow + quad * 4 + reg;
            int b = row / 784;
            int loc = row - b * 784;
#pragma unroll
            for (int n = 0; n < 12; n++) {
                int col = n * 16 + l16;
                int h = col >> 6, d = col & 63;
                vtbuf[(((size_t)b * 3 + h) * 64 + d) * 784 + loc] = (bf16)acc[n][reg];
            }
        }
    } else {
        bf16* outp = (mode == 0) ? qbuf : kbuf;
        const float s = (mode == 0) ? 0.125f : 1.0f;
#pragma unroll
        for (int reg = 0; reg < 4; reg++) {
            size_t row = m0 + wrow + quad * 4 + reg;
#pragma unroll
            for (int n = 0; n < 12; n++)
                outp[row * 192 + n * 16 + l16] = (bf16)(acc[n][reg] * s);
        }
    }
}

// ---------------------------------------------------------------------------
// Kernel 3: flash attention, S^T formulation, BARRIER-FREE.
// R7 restructure: K and Vt per (b,h,chunk) are ~14 KB each -> L1-resident
// (32 KB/CU) and L2-resident (200 KB per (b,h), 4.8 MB total). The old
// LDS staging bought only a 4x intra-block dedup that L1 provides free,
// at the cost of 2 full-drain barriers per chunk + DMA address VALU +
// 34 KB LDS. Now: MFMA A-operands (K rows / Vt rows) load directly from
// global as bf16x8 (16 B/lane, 64 B contiguous per quad group).
// Ps is written and read ONLY by the owning wave (rows wrow..wrow+15),
// and its pad-zeroing is done by the wave's own lanes -> the kernel has
// ZERO __syncthreads; every wave runs free, lgkmcnt orders LDS RAW.
// LDS 51.2 KB -> 17.4 KB; waves_per_eu(4,8) caps VGPR at 128 so
// occupancy rises from 12 to >=16 waves/CU to hide L1/L2 latency.
// Vt pad columns (keys 112..127 of last chunk) read <=30 B past vtbuf
// into the adjacent wt workspace region (allocated, finite) and are
// annihilated by the zeroed Ps pad columns.
// ---------------------------------------------------------------------------
__global__ __launch_bounds__(256)
__attribute__((amdgpu_waves_per_eu(4, 8)))
void attn3_kernel(const bf16* __restrict__ qb,
                  const bf16* __restrict__ kb,
                  const bf16* __restrict__ vtb,
                  float* __restrict__ out) {
    const int LQ = 3136, LK = 784, C = 192;
    int qt = blockIdx.x, h = blockIdx.y, b = blockIdx.z;

    __shared__ bf16 Ps[64][136];   // [q][key], cols 112..127 zeroed per-wave

    int t    = threadIdx.x;
    int lane = t & 63;
    int wid  = t >> 6;
    int l16  = lane & 15;
    int quad = lane >> 4;
    int wrow = wid * 16;

    // zero THIS wave's Ps pad cols (annihilate Vt garbage in the PV MFMA);
    // wave-local write -> ordered vs this wave's reads by lgkmcnt, no barrier
    if (lane < 32) {
        int row = wrow + (lane >> 1);
        int part = lane & 1;
        *(uint4*)&Ps[row][112 + part * 8] = make_uint4(0u, 0u, 0u, 0u);
    }

    // Q fragments (B operand: n = q = l16, k = d) held in registers
    bf16x8 qfrag[2];
    {
        const bf16* qrow = qb + ((size_t)b * LQ + qt * 64 + wrow + l16) * C + h * 64;
        qfrag[0] = *(const bf16x8*)(qrow + quad * 8);
        qfrag[1] = *(const bf16x8*)(qrow + 32 + quad * 8);
    }

    const bf16* kbase  = kb + (size_t)b * LK * C + h * 64;
    const bf16* vtbase = vtb + ((size_t)(b * 3 + h)) * 64 * LK;

    float m_run = -INFINITY, l_run = 0.f;
    f32x4 o_acc[4];
#pragma unroll
    for (int dt = 0; dt < 4; dt++) o_acc[dt] = f32x4{0.f, 0.f, 0.f, 0.f};

    for (int c = 0; c < 7; c++) {
        const int j0 = c * 112;
        // per-lane base pointers: lane reads K row (j0 + kb7*16 + l16) and
        // Vt row (dt*16 + l16); quad picks the 16-B sub-chunk of the row.
        const bf16* kc = kbase + (size_t)(j0 + l16) * C + quad * 8;
        const bf16* vc = vtbase + (size_t)l16 * LK + j0 + quad * 8;

        // S^T = K Q^T : 7 key-tiles x (K-dim 64 = 2 steps), K from L1/L2
        f32x4 st[7];
#pragma unroll
        for (int kb7 = 0; kb7 < 7; kb7++) st[kb7] = f32x4{0.f, 0.f, 0.f, 0.f};
#pragma unroll
        for (int kk = 0; kk < 2; kk++) {
#pragma unroll
            for (int kb7 = 0; kb7 < 7; kb7++) {
                bf16x8 afrag = *(const bf16x8*)(kc + (size_t)kb7 * 16 * C + kk * 32);
                st[kb7] = __builtin_amdgcn_mfma_f32_16x16x32_bf16(afrag, qfrag[kk], st[kb7], 0, 0, 0);
            }
        }

        // online softmax for q = l16 (28 keys in-lane, cross-quad shuffles)
        float mx = -INFINITY;
#pragma unroll
        for (int kb7 = 0; kb7 < 7; kb7++)
#pragma unroll
            for (int r = 0; r < 4; r++) mx = fmaxf(mx, st[kb7][r]);
        mx = fmaxf(mx, __shfl_xor(mx, 16, 64));
        mx = fmaxf(mx, __shfl_xor(mx, 32, 64));
        float m_new = fmaxf(m_run, mx);
        float alpha = __expf(m_run - m_new);   // chunk 0: exp(-inf)=0

        float rs = 0.f;
#pragma unroll
        for (int kb7 = 0; kb7 < 7; kb7++) {
            bf16x4 pv;
#pragma unroll
            for (int r = 0; r < 4; r++) {
                float p = __expf(st[kb7][r] - m_new);
                rs += p;
                pv[r] = (bf16)p;
            }
            *(bf16x4*)&Ps[wrow + l16][kb7 * 16 + quad * 4] = pv;
        }
        rs += __shfl_xor(rs, 16, 64);
        rs += __shfl_xor(rs, 32, 64);
        l_run = l_run * alpha + rs;
        m_run = m_new;
#pragma unroll
        for (int dt = 0; dt < 4; dt++)
#pragma unroll
            for (int r = 0; r < 4; r++) o_acc[dt][r] *= alpha;

        // O^T += Vt P^T : keys 128 (16 zero-P-padded) = 4 steps, Vt from L1/L2
#pragma unroll
        for (int kk = 0; kk < 4; kk++) {
            bf16x8 pfrag = *(const bf16x8*)&Ps[wrow + l16][kk * 32 + quad * 8];
#pragma unroll
            for (int dt = 0; dt < 4; dt++) {
                bf16x8 vfrag = *(const bf16x8*)(vc + (size_t)dt * 16 * LK + kk * 32);
                o_acc[dt] = __builtin_amdgcn_mfma_f32_16x16x32_bf16(vfrag, pfrag, o_acc[dt], 0, 0, 0);
            }
        }
    }

    // epilogue: lane holds q = l16, d = dt*16 + quad*4 + reg -> float4 stores
    float invl = 1.f / l_run;
    float* ob = out + ((size_t)b * LQ + qt * 64 + wrow + l16) * C + h * 64;
#pragma unroll
    for (int dt = 0; dt < 4; dt++) {
        float4 v4 = {o_acc[dt][0] * invl, o_acc[dt][1] * invl,
                     o_acc[dt][2] * invl, o_acc[dt][3] * invl};
        *(float4*)(ob + dt * 16 + quad * 4) = v4;
    }
}

// ---------------------------------------------------------------------------
extern "C" void kernel_launch(void* const* d_in, const int* in_sizes, int n_in,
                              void* d_out, int out_size, void* d_ws, size_t ws_size,
                              hipStream_t stream) {
    const float* x = (const float*)d_in[0];

    const float* q_dw = (const float*)d_in[1];
    const float* q_scale = (const float*)d_in[2];
    const float* q_bias = (const float*)d_in[3];
    const float* q_mean = (const float*)d_in[4];
    const float* q_var = (const float*)d_in[5];
    const float* q_pw = (const float*)d_in[6];

    const float* k_dw = (const float*)d_in[7];
    const float* k_scale = (const float*)d_in[8];
    const float* k_bias = (const float*)d_in[9];
    const float* k_mean = (const float*)d_in[10];
    const float* k_var = (const float*)d_in[11];
    const float* k_pw = (const float*)d_in[12];

    const float* v_dw = (const float*)d_in[13];
    const float* v_scale = (const float*)d_in[14];
    const float* v_bias = (const float*)d_in[15];
    const float* v_mean = (const float*)d_in[16];
    const float* v_var = (const float*)d_in[17];
    const float* v_pw = (const float*)d_in[18];

    float* out = (float*)d_out;

    // workspace layout (bytes, all 16B aligned)
    char* ws = (char*)d_ws;
    bf16* qhi = (bf16*)(ws);                  // 9,633,792
    bf16* qlo = (bf16*)(ws + 9633792);        // 9,633,792
    bf16* khi = (bf16*)(ws + 19267584);       // 2,408,448
    bf16* klo = (bf16*)(ws + 21676032);       // 2,408,448
    bf16* vhi = (bf16*)(ws + 24084480);       // 2,408,448
    bf16* vlo = (bf16*)(ws + 26492928);       // 2,408,448
    bf16* qbuf = (bf16*)(ws + 28901376);      // 9,633,792
    bf16* kbuf = (bf16*)(ws + 38535168);      // 2,408,448
    bf16* vtbuf = (bf16*)(ws + 40943616);     // 2,408,448
    bf16* wt = (bf16*)(ws + 43352064);        // 221,184

    // stage 1: conv(Q) + conv(K,V) + weight cast, one launch (6312 blocks)
    conv_all_kernel<<<6312, 256, 0, stream>>>(
        x,
        q_dw, q_scale, q_bias, q_mean, q_var,
        k_dw, k_scale, k_bias, k_mean, k_var,
        v_dw, v_scale, v_bias, v_mean, v_var,
        q_pw, k_pw, v_pw,
        qhi, qlo, khi, klo, vhi, vlo, wt);

    // stage 2: all three pointwise GEMMs, one launch (588 blocks)
    gemm_all_kernel<<<588, 256, 0, stream>>>(
        qhi, qlo, khi, klo, vhi, vlo, wt, qbuf, kbuf, vtbuf);

    // stage 3: attention (49 q-tiles, 3 heads, 8 batches)
    attn3_kernel<<<dim3(49, 3, 8), 256, 0, stream>>>(qbuf, kbuf, vtbuf, out);
}

// Round 2
// 193.651 us; speedup vs baseline: 1.1587x; 1.1587x over previous
//
#include <hip/hip_runtime.h>
#include <cmath>

#define EPS_BN 1e-5f

typedef __bf16 bf16;
typedef __bf16 bf16x4 __attribute__((ext_vector_type(4)));
typedef __bf16 bf16x8 __attribute__((ext_vector_type(8)));
typedef float  f32x4  __attribute__((ext_vector_type(4)));

// async global->LDS DMA, 16 B per lane, LDS dest = wave-uniform base + lane*16
__device__ __forceinline__ void dma16(const bf16* g, bf16* l) {
    __builtin_amdgcn_global_load_lds(
        (const __attribute__((address_space(1))) void*)g,
        (__attribute__((address_space(3))) void*)l, 16, 0, 0);
}

// ---------------------------------------------------------------------------
// Kernel 1: all preprocessing elementwise work in one launch. (unchanged R6)
// ---------------------------------------------------------------------------
__global__ __launch_bounds__(256) void conv_all_kernel(
    const float* __restrict__ x,
    const float* __restrict__ qdw, const float* __restrict__ qscale,
    const float* __restrict__ qbias, const float* __restrict__ qmean,
    const float* __restrict__ qvar,
    const float* __restrict__ kdw, const float* __restrict__ kscale,
    const float* __restrict__ kbias, const float* __restrict__ kmean,
    const float* __restrict__ kvar,
    const float* __restrict__ vdw, const float* __restrict__ vscale,
    const float* __restrict__ vbias, const float* __restrict__ vmean,
    const float* __restrict__ vvar,
    const float* __restrict__ qpw, const float* __restrict__ kpw,
    const float* __restrict__ vpw,
    bf16* __restrict__ qhi, bf16* __restrict__ qlo,
    bf16* __restrict__ khi, bf16* __restrict__ klo,
    bf16* __restrict__ vhi, bf16* __restrict__ vlo,
    bf16* __restrict__ wt) {
    const int WW = 56, C = 192;
    int bid = blockIdx.x;

    if (bid < 4704) {
        int idx = bid * 256 + threadIdx.x;
        int p  = idx / 48;
        int c4 = (idx - p * 48) * 4;
        int b  = p / 3136;
        int rem = p - b * 3136;
        int oy = rem / 56;
        int ox = rem - oy * 56;
        const float* xb = x + (size_t)b * 3136 * C;

        float4 sc = *(const float4*)&qscale[c4];
        float4 vr = *(const float4*)&qvar[c4];
        float4 bi = *(const float4*)&qbias[c4];
        float4 mn = *(const float4*)&qmean[c4];
        float aA[4] = {sc.x * rsqrtf(vr.x + EPS_BN), sc.y * rsqrtf(vr.y + EPS_BN),
                       sc.z * rsqrtf(vr.z + EPS_BN), sc.w * rsqrtf(vr.w + EPS_BN)};
        float aB[4] = {bi.x - mn.x * aA[0], bi.y - mn.y * aA[1],
                       bi.z - mn.z * aA[2], bi.w - mn.w * aA[3]};
        float s[4] = {0.f, 0.f, 0.f, 0.f};
#pragma unroll
        for (int ky = 0; ky < 3; ky++) {
            int iy = oy + ky - 1;
            bool yok = (iy >= 0) && (iy < 56);
#pragma unroll
            for (int kx = 0; kx < 3; kx++) {
                int ix = ox + kx - 1;
                if (yok && ix >= 0 && ix < WW) {
                    float4 xv = *(const float4*)&xb[((size_t)iy * WW + ix) * C + c4];
                    float4 wv = *(const float4*)&qdw[(ky * 3 + kx) * C + c4];
                    s[0] += xv.x * wv.x; s[1] += xv.y * wv.y;
                    s[2] += xv.z * wv.z; s[3] += xv.w * wv.w;
                }
            }
        }
        bf16x4 hv, lv;
#pragma unroll
        for (int j = 0; j < 4; j++) {
            float av = s[j] * aA[j] + aB[j];
            bf16 hh = (bf16)av;
            hv[j] = hh;
            lv[j] = (bf16)(av - (float)hh);
        }
        *(bf16x4*)&qhi[(size_t)p * C + c4] = hv;
        *(bf16x4*)&qlo[(size_t)p * C + c4] = lv;
    } else if (bid < 5880) {
        int idx = (bid - 4704) * 256 + threadIdx.x;
        int p  = idx / 48;
        int c4 = (idx - p * 48) * 4;
        int b  = p / 784;
        int rem = p - b * 784;
        int oy = rem / 28;
        int ox = rem - oy * 28;
        const float* xb = x + (size_t)b * 3136 * C;

        float ks[4] = {0.f, 0.f, 0.f, 0.f};
        float vs[4] = {0.f, 0.f, 0.f, 0.f};
#pragma unroll
        for (int ky = 0; ky < 3; ky++) {
            int iy = oy * 2 + ky;
            bool yok = iy < 56;
#pragma unroll
            for (int kx = 0; kx < 3; kx++) {
                int ix = ox * 2 + kx;
                if (yok && ix < WW) {
                    float4 xv = *(const float4*)&xb[((size_t)iy * WW + ix) * C + c4];
                    float4 kw = *(const float4*)&kdw[(ky * 3 + kx) * C + c4];
                    float4 vw = *(const float4*)&vdw[(ky * 3 + kx) * C + c4];
                    ks[0] += xv.x * kw.x; ks[1] += xv.y * kw.y;
                    ks[2] += xv.z * kw.z; ks[3] += xv.w * kw.w;
                    vs[0] += xv.x * vw.x; vs[1] += xv.y * vw.y;
                    vs[2] += xv.z * vw.z; vs[3] += xv.w * vw.w;
                }
            }
        }
        float4 ksc = *(const float4*)&kscale[c4];
        float4 kvr = *(const float4*)&kvar[c4];
        float4 kbi = *(const float4*)&kbias[c4];
        float4 kmn = *(const float4*)&kmean[c4];
        float4 vsc = *(const float4*)&vscale[c4];
        float4 vvr = *(const float4*)&vvar[c4];
        float4 vbi = *(const float4*)&vbias[c4];
        float4 vmn = *(const float4*)&vmean[c4];
        float kA[4] = {ksc.x * rsqrtf(kvr.x + EPS_BN), ksc.y * rsqrtf(kvr.y + EPS_BN),
                       ksc.z * rsqrtf(kvr.z + EPS_BN), ksc.w * rsqrtf(kvr.w + EPS_BN)};
        float kB[4] = {kbi.x - kmn.x * kA[0], kbi.y - kmn.y * kA[1],
                       kbi.z - kmn.z * kA[2], kbi.w - kmn.w * kA[3]};
        float vA[4] = {vsc.x * rsqrtf(vvr.x + EPS_BN), vsc.y * rsqrtf(vvr.y + EPS_BN),
                       vsc.z * rsqrtf(vvr.z + EPS_BN), vsc.w * rsqrtf(vvr.w + EPS_BN)};
        float vB[4] = {vbi.x - vmn.x * vA[0], vbi.y - vmn.y * vA[1],
                       vbi.z - vmn.z * vA[2], vbi.w - vmn.w * vA[3]};
        bf16x4 kh, kl, vh, vl;
#pragma unroll
        for (int j = 0; j < 4; j++) {
            float kf = ks[j] * kA[j] + kB[j];
            float vf = vs[j] * vA[j] + vB[j];
            bf16 h1 = (bf16)kf; kh[j] = h1; kl[j] = (bf16)(kf - (float)h1);
            bf16 h2 = (bf16)vf; vh[j] = h2; vl[j] = (bf16)(vf - (float)h2);
        }
        *(bf16x4*)&khi[(size_t)p * C + c4] = kh;
        *(bf16x4*)&klo[(size_t)p * C + c4] = kl;
        *(bf16x4*)&vhi[(size_t)p * C + c4] = vh;
        *(bf16x4*)&vlo[(size_t)p * C + c4] = vl;
    } else {
        int idx = (bid - 5880) * 256 + threadIdx.x;
        if (idx < 3 * 36864) {
            int mat = idx / 36864, r = idx % 36864;
            int n = r / 192, k = r - n * 192;
            const float* src = (mat == 0) ? qpw : (mat == 1) ? kpw : vpw;
            wt[idx] = (bf16)src[k * 192 + n];
        }
    }
}

// ---------------------------------------------------------------------------
// Kernel 2: all three pointwise GEMMs in one launch. (unchanged R6)
// ---------------------------------------------------------------------------
__global__ __launch_bounds__(256) void gemm_all_kernel(
    const bf16* __restrict__ qhi, const bf16* __restrict__ qlo,
    const bf16* __restrict__ khi, const bf16* __restrict__ klo,
    const bf16* __restrict__ vhi, const bf16* __restrict__ vlo,
    const bf16* __restrict__ wt,
    bf16* __restrict__ qbuf, bf16* __restrict__ kbuf, bf16* __restrict__ vtbuf) {
    __shared__ bf16 Ws[192][200];
    int t = threadIdx.x;
    int bid = blockIdx.x;

    int mode, mt;
    const bf16 *Ahi, *Alo, *Wsrc;
    if (bid < 392)      { mode = 0; mt = bid;       Ahi = qhi; Alo = qlo; Wsrc = wt; }
    else if (bid < 490) { mode = 1; mt = bid - 392; Ahi = khi; Alo = klo; Wsrc = wt + 36864; }
    else                { mode = 2; mt = bid - 490; Ahi = vhi; Alo = vlo; Wsrc = wt + 73728; }

#pragma unroll
    for (int it = 0; it < 18; it++) {
        int idx = it * 256 + t;
        int n = idx / 24, ck = idx - n * 24;
        *(uint4*)&Ws[n][ck * 8] = *(const uint4*)&Wsrc[n * 192 + ck * 8];
    }
    __syncthreads();

    int lane = t & 63, wid = t >> 6;
    int l16 = lane & 15, quad = lane >> 4;
    int wrow = wid * 16;
    int m0 = mt * 64;

    f32x4 acc[12];
#pragma unroll
    for (int n = 0; n < 12; n++) acc[n] = f32x4{0.f, 0.f, 0.f, 0.f};

    const bf16* arh = Ahi + (size_t)(m0 + wrow + l16) * 192;
    const bf16* arl = Alo + (size_t)(m0 + wrow + l16) * 192;
#pragma unroll
    for (int kc = 0; kc < 6; kc++) {
        bf16x8 ah = *(const bf16x8*)(arh + kc * 32 + quad * 8);
        bf16x8 al = *(const bf16x8*)(arl + kc * 32 + quad * 8);
#pragma unroll
        for (int n = 0; n < 12; n++) {
            bf16x8 bfr = *(const bf16x8*)&Ws[n * 16 + l16][kc * 32 + quad * 8];
            acc[n] = __builtin_amdgcn_mfma_f32_16x16x32_bf16(al, bfr, acc[n], 0, 0, 0);
            acc[n] = __builtin_amdgcn_mfma_f32_16x16x32_bf16(ah, bfr, acc[n], 0, 0, 0);
        }
    }

    if (mode == 2) {
#pragma unroll
        for (int reg = 0; reg < 4; reg++) {
            int row = m0 + wrow + quad * 4 + reg;
            int b = row / 784;
            int loc = row - b * 784;
#pragma unroll
            for (int n = 0; n < 12; n++) {
                int col = n * 16 + l16;
                int h = col >> 6, d = col & 63;
                vtbuf[(((size_t)b * 3 + h) * 64 + d) * 784 + loc] = (bf16)acc[n][reg];
            }
        }
    } else {
        bf16* outp = (mode == 0) ? qbuf : kbuf;
        const float s = (mode == 0) ? 0.125f : 1.0f;
#pragma unroll
        for (int reg = 0; reg < 4; reg++) {
            size_t row = m0 + wrow + quad * 4 + reg;
#pragma unroll
            for (int n = 0; n < 12; n++)
                outp[row * 192 + n * 16 + l16] = (bf16)(acc[n][reg] * s);
        }
    }
}

// ---------------------------------------------------------------------------
// Kernel 3: flash attention, S^T formulation. R8: pipelined staging.
//  - K double-buffered in LDS via global_load_lds: chunk c+1's DMA issues at
//    the top of chunk c and drains at the single end-of-chunk barrier (it has
//    the whole chunk's compute in flight to complete). ONE barrier per chunk
//    (was 2 full-drain barriers in R6); the barrier also guarantees no wave
//    still reads Ks[cur] when the next chunk's DMA overwrites it.
//  - Ks layout: linear [112 rows][64 ch] per buffer, 14336 B, XOR chunk
//    swizzle (both-sides, rule #21): DMA source pre-swizzled with
//    lc = (lane&7)^(lane>>3) (divisor-free stripe addressing, 14 stripes),
//    reads use physical chunk = (kk*4+quad)^(l16&7). 8 lanes per bank-quad
//    -> conflict-free ds_read_b128.
//  - Vt NOT staged in LDS: 16 bf16x8 register prefetches issued at chunk top,
//    ~700 cy before PV consumes them (L2 latency hides under QK^T+softmax;
//    R7 showed the wave-duplicated Vt traffic is cache-absorbed, FETCH_SIZE
//    unchanged). Vt is off the critical path, unlike K in R7.
//  - LDS: 2*14336 (Ks) + 17408 (Ps) = 46080 B -> 3 blocks/CU (same as R6).
//  - Ps pad cols zeroed wave-locally (R7-validated), no barrier needed.
//  - Last chunk's Vt kk=3 reads overrun vtbuf by 32 B into wt (allocated,
//    finite), annihilated by zeroed Ps cols 112..127.
// ---------------------------------------------------------------------------
__global__ __launch_bounds__(256)
__attribute__((amdgpu_waves_per_eu(3, 3)))
void attn3_kernel(const bf16* __restrict__ qb,
                  const bf16* __restrict__ kb,
                  const bf16* __restrict__ vtb,
                  float* __restrict__ out) {
    const int LQ = 3136, LK = 784, C = 192;
    int qt = blockIdx.x, h = blockIdx.y, b = blockIdx.z;

    __shared__ bf16 Ks[2][7168];    // [buf][112][64], XOR-swizzled 16B chunks
    __shared__ bf16 Ps[64][136];    // [q][key], cols 112..127 zeroed per-wave

    int t    = threadIdx.x;
    int lane = t & 63;
    int wid  = t >> 6;
    int l16  = lane & 15;
    int quad = lane >> 4;
    int wrow = wid * 16;

    // zero THIS wave's Ps pad cols (wave-local; lgkmcnt orders vs own reads)
    if (lane < 32) {
        int row = wrow + (lane >> 1);
        int part = lane & 1;
        *(uint4*)&Ps[row][112 + part * 8] = make_uint4(0u, 0u, 0u, 0u);
    }

    const bf16* kbase  = kb + (size_t)b * LK * C + h * 64;
    const bf16* vtbase = vtb + ((size_t)(b * 3 + h)) * 64 * LK;

    // DMA source swizzle: dest chunk d = s*64+lane -> row s*8+(lane>>3),
    // physical chunk (lane&7) holds logical chunk (lane&7)^(lane>>3).
    const bf16* ksrc = kbase + (lane >> 3) * C + (((lane & 7) ^ (lane >> 3)) * 8);

    // prologue: chunk-0 K DMA (14 stripes round-robined over 4 waves)
    for (int s = wid; s < 14; s += 4)
        dma16(ksrc + s * 8 * C, &Ks[0][s * 512]);

    // Q fragments (B operand: n = q = l16, k = d) held in registers
    bf16x8 qfrag[2];
    {
        const bf16* qrow = qb + ((size_t)b * LQ + qt * 64 + wrow + l16) * C + h * 64;
        qfrag[0] = *(const bf16x8*)(qrow + quad * 8);
        qfrag[1] = *(const bf16x8*)(qrow + 32 + quad * 8);
    }

    // per-lane Ks read offsets (elements) for kk=0,1: physical chunk XOR
    int kA0 = l16 * 64 + (((quad    ) ^ (l16 & 7)) * 8);
    int kA1 = l16 * 64 + (((quad + 4) ^ (l16 & 7)) * 8);

    float m_run = -INFINITY, l_run = 0.f;
    f32x4 o_acc[4];
#pragma unroll
    for (int dt = 0; dt < 4; dt++) o_acc[dt] = f32x4{0.f, 0.f, 0.f, 0.f};

    __syncthreads();   // drains prologue DMA -> Ks[0] visible

    for (int c = 0; c < 7; c++) {
        const int cur = c & 1, nxt = cur ^ 1;
        const int j0 = c * 112;

        // Vt register prefetch for THIS chunk (consumed by PV ~700 cy later)
        const bf16* vc = vtbase + (size_t)l16 * LK + j0 + quad * 8;
        bf16x8 vfrag[4][4];
#pragma unroll
        for (int kk = 0; kk < 4; kk++)
#pragma unroll
            for (int dt = 0; dt < 4; dt++)
                vfrag[kk][dt] = *(const bf16x8*)(vc + (size_t)(dt * 16) * LK + kk * 32);

        // K DMA prefetch for NEXT chunk into the other buffer
        if (c < 6) {
            const bf16* kn = ksrc + (size_t)(c + 1) * 112 * C;
            for (int s = wid; s < 14; s += 4)
                dma16(kn + s * 8 * C, &Ks[nxt][s * 512]);
        }

        // S^T = K Q^T : 7 key-tiles x (K-dim 64 = 2 steps), K from LDS
        f32x4 st[7];
#pragma unroll
        for (int kb7 = 0; kb7 < 7; kb7++) st[kb7] = f32x4{0.f, 0.f, 0.f, 0.f};
#pragma unroll
        for (int kk = 0; kk < 2; kk++) {
            int kA = (kk == 0) ? kA0 : kA1;
#pragma unroll
            for (int kb7 = 0; kb7 < 7; kb7++) {
                bf16x8 afrag = *(const bf16x8*)&Ks[cur][kb7 * 1024 + kA];
                st[kb7] = __builtin_amdgcn_mfma_f32_16x16x32_bf16(afrag, qfrag[kk], st[kb7], 0, 0, 0);
            }
        }

        // online softmax for q = l16 (28 keys in-lane, cross-quad shuffles)
        float mx = -INFINITY;
#pragma unroll
        for (int kb7 = 0; kb7 < 7; kb7++)
#pragma unroll
            for (int r = 0; r < 4; r++) mx = fmaxf(mx, st[kb7][r]);
        mx = fmaxf(mx, __shfl_xor(mx, 16, 64));
        mx = fmaxf(mx, __shfl_xor(mx, 32, 64));
        float m_new = fmaxf(m_run, mx);
        float alpha = __expf(m_run - m_new);   // chunk 0: exp(-inf)=0

        float rs = 0.f;
#pragma unroll
        for (int kb7 = 0; kb7 < 7; kb7++) {
            bf16x4 pv;
#pragma unroll
            for (int r = 0; r < 4; r++) {
                float p = __expf(st[kb7][r] - m_new);
                rs += p;
                pv[r] = (bf16)p;
            }
            *(bf16x4*)&Ps[wrow + l16][kb7 * 16 + quad * 4] = pv;
        }
        rs += __shfl_xor(rs, 16, 64);
        rs += __shfl_xor(rs, 32, 64);
        l_run = l_run * alpha + rs;
        m_run = m_new;
#pragma unroll
        for (int dt = 0; dt < 4; dt++)
#pragma unroll
            for (int r = 0; r < 4; r++) o_acc[dt][r] *= alpha;

        // O^T += Vt P^T : keys 128 (16 zero-P-padded) = 4 steps, Vt from regs
#pragma unroll
        for (int kk = 0; kk < 4; kk++) {
            bf16x8 pfrag = *(const bf16x8*)&Ps[wrow + l16][kk * 32 + quad * 8];
#pragma unroll
            for (int dt = 0; dt < 4; dt++)
                o_acc[dt] = __builtin_amdgcn_mfma_f32_16x16x32_bf16(vfrag[kk][dt], pfrag, o_acc[dt], 0, 0, 0);
        }

        // single barrier: (a) all waves done reading Ks[cur], (b) drains the
        // next-chunk DMA (vmcnt(0)) -> Ks[nxt] visible for chunk c+1
        __syncthreads();
    }

    // epilogue: lane holds q = l16, d = dt*16 + quad*4 + reg -> float4 stores
    float invl = 1.f / l_run;
    float* ob = out + ((size_t)b * LQ + qt * 64 + wrow + l16) * C + h * 64;
#pragma unroll
    for (int dt = 0; dt < 4; dt++) {
        float4 v4 = {o_acc[dt][0] * invl, o_acc[dt][1] * invl,
                     o_acc[dt][2] * invl, o_acc[dt][3] * invl};
        *(float4*)(ob + dt * 16 + quad * 4) = v4;
    }
}

// ---------------------------------------------------------------------------
extern "C" void kernel_launch(void* const* d_in, const int* in_sizes, int n_in,
                              void* d_out, int out_size, void* d_ws, size_t ws_size,
                              hipStream_t stream) {
    const float* x = (const float*)d_in[0];

    const float* q_dw = (const float*)d_in[1];
    const float* q_scale = (const float*)d_in[2];
    const float* q_bias = (const float*)d_in[3];
    const float* q_mean = (const float*)d_in[4];
    const float* q_var = (const float*)d_in[5];
    const float* q_pw = (const float*)d_in[6];

    const float* k_dw = (const float*)d_in[7];
    const float* k_scale = (const float*)d_in[8];
    const float* k_bias = (const float*)d_in[9];
    const float* k_mean = (const float*)d_in[10];
    const float* k_var = (const float*)d_in[11];
    const float* k_pw = (const float*)d_in[12];

    const float* v_dw = (const float*)d_in[13];
    const float* v_scale = (const float*)d_in[14];
    const float* v_bias = (const float*)d_in[15];
    const float* v_mean = (const float*)d_in[16];
    const float* v_var = (const float*)d_in[17];
    const float* v_pw = (const float*)d_in[18];

    float* out = (float*)d_out;

    // workspace layout (bytes, all 16B aligned)
    char* ws = (char*)d_ws;
    bf16* qhi = (bf16*)(ws);                  // 9,633,792
    bf16* qlo = (bf16*)(ws + 9633792);        // 9,633,792
    bf16* khi = (bf16*)(ws + 19267584);       // 2,408,448
    bf16* klo = (bf16*)(ws + 21676032);       // 2,408,448
    bf16* vhi = (bf16*)(ws + 24084480);       // 2,408,448
    bf16* vlo = (bf16*)(ws + 26492928);       // 2,408,448
    bf16* qbuf = (bf16*)(ws + 28901376);      // 9,633,792
    bf16* kbuf = (bf16*)(ws + 38535168);      // 2,408,448
    bf16* vtbuf = (bf16*)(ws + 40943616);     // 2,408,448
    bf16* wt = (bf16*)(ws + 43352064);        // 221,184

    // stage 1: conv(Q) + conv(K,V) + weight cast, one launch (6312 blocks)
    conv_all_kernel<<<6312, 256, 0, stream>>>(
        x,
        q_dw, q_scale, q_bias, q_mean, q_var,
        k_dw, k_scale, k_bias, k_mean, k_var,
        v_dw, v_scale, v_bias, v_mean, v_var,
        q_pw, k_pw, v_pw,
        qhi, qlo, khi, klo, vhi, vlo, wt);

    // stage 2: all three pointwise GEMMs, one launch (588 blocks)
    gemm_all_kernel<<<588, 256, 0, stream>>>(
        qhi, qlo, khi, klo, vhi, vlo, wt, qbuf, kbuf, vtbuf);

    // stage 3: attention (49 q-tiles, 3 heads, 8 batches)
    attn3_kernel<<<dim3(49, 3, 8), 256, 0, stream>>>(qbuf, kbuf, vtbuf, out);
}